// Round 1
// baseline (1381.870 us; speedup 1.0000x reference)
//
#include <hip/hip_runtime.h>

// SteeredConvTranspose2d on MI355X — round 1: fp32 direct per-parity conv.
//
// ws layout (floats):
//   [0 .. 401408)                KA_par : per-parity 7x7 weights [par][uv2][i64][taps][o64]
//   [401408 .. 913408)           KB_par : per-parity 5x5 weights [par][g5][i64][taps][o64]
//   [1048576 .. 1048576+8388608) U plane (8,64,128,128)
//   [9437184 .. 9437184+8388608) V plane
// total ~71 MB.

namespace {

constexpr int OFFA[4] = {0, 131072, 229376, 327680};   // sizes 2*64*nt*64, nt={16,12,12,9}
constexpr int OFFB[4] = {0,  81920, 204800, 327680};   // sizes 5*64*nt*64, nt={4,6,6,9}
constexpr int NKA = 401408;
constexpr int NKB = 512000;

// ---------------- prep: build per-parity fused basis*weight tensors ----------------
__global__ __launch_bounds__(256) void prep_kernel(
    const float* __restrict__ w0, const float* __restrict__ wc,
    const float* __restrict__ wsn, const float* __restrict__ wa,
    float* __restrict__ ka, float* __restrict__ kb)
{
    // normalization sums for radial profiles
    float SA[3], S5[3];
#pragma unroll
    for (int r = 0; r < 3; ++r) { SA[r] = 0.f; S5[r] = 0.f; }
    for (int ky = 0; ky < 7; ++ky)
        for (int kx = 0; kx < 7; ++kx) {
            float dy = (float)(ky - 3), dx = (float)(kx - 3);
            float rr = sqrtf(dy * dy + dx * dx);
#pragma unroll
            for (int r = 0; r < 3; ++r) { float d = rr - (float)(r + 1); SA[r] += expf(-2.f * d * d); }
        }
    for (int ky = 0; ky < 5; ++ky)
        for (int kx = 0; kx < 5; ++kx) {
            float dy = (float)(ky - 2), dx = (float)(kx - 2);
            float rr = sqrtf(dy * dy + dx * dx);
#pragma unroll
            for (int r = 0; r < 3; ++r) { float d = rr - (float)r; S5[r] += expf(-2.f * d * d); }
        }

    const int stride = gridDim.x * blockDim.x;
    for (int idx = blockIdx.x * blockDim.x + threadIdx.x; idx < NKA + NKB; idx += stride) {
        if (idx < NKA) {
            // 7x7 kernels (u,v). layout [par][uv][i][t][o], t = tyi*nx+txi
            int par = (idx < OFFA[1]) ? 0 : (idx < OFFA[2]) ? 1 : (idx < OFFA[3]) ? 2 : 3;
            int py = par >> 1, px = par & 1;
            int nx = 4 - px;
            int nt = (4 - py) * nx;
            int rem = idx - OFFA[par];
            int o = rem & 63; rem >>= 6;
            int t = rem % nt; rem /= nt;
            int i = rem & 63;
            int uv = rem >> 6;
            int tyi = t / nx, txi = t % nx;
            float dy = (float)(2 * tyi + py - 3), dx = (float)(2 * txi + px - 3);
            float rr = sqrtf(dy * dy + dx * dx);
            float phi = atan2f(dy, dx);
            float tr = (uv == 0) ? cosf(phi) : sinf(phi);
            const float* wrow = wa + (o * 64 + i) * 3;
            float v = 0.f;
#pragma unroll
            for (int r = 0; r < 3; ++r) { float d = rr - (float)(r + 1); v += wrow[r] * (expf(-2.f * d * d) / SA[r]); }
            ka[idx] = v * tr;
        } else {
            // 5x5 kernels (5 groups). layout [par][g][i][t][o]
            int jdx = idx - NKA;
            int par = (jdx < OFFB[1]) ? 0 : (jdx < OFFB[2]) ? 1 : (jdx < OFFB[3]) ? 2 : 3;
            int py = par >> 1, px = par & 1;
            int nx = 2 + px;
            int nt = (2 + py) * nx;
            int rem = jdx - OFFB[par];
            int o = rem & 63; rem >>= 6;
            int t = rem % nt; rem /= nt;
            int i = rem & 63;
            int g = rem >> 6;
            int tyi = t / nx, txi = t % nx;
            float dy = (float)(2 * tyi + 1 - py - 2), dx = (float)(2 * txi + 1 - px - 2);
            float rr = sqrtf(dy * dy + dx * dx);
            float phi = atan2f(dy, dx);
            float v = 0.f;
            if (g == 0) {
                const float* wrow = w0 + (o * 64 + i) * 3;
#pragma unroll
                for (int r = 0; r < 3; ++r) { float d = rr - (float)r; v += wrow[r] * (expf(-2.f * d * d) / S5[r]); }
            } else {
                int k = (g - 1) >> 1;   // 0 -> angular order 1, 1 -> order 2
                int sn = (g - 1) & 1;   // 0 cos, 1 sin
                const float* wsel = ((sn == 0) ? wc : wsn) + ((k * 64 + o) * 64 + i) * 2;
                float ang = (float)(k + 1) * phi;
                float tr = (sn == 0) ? cosf(ang) : sinf(ang);
                float s = 0.f;
#pragma unroll
                for (int r = 0; r < 2; ++r) { float d = rr - (float)(r + 1); s += wsel[r] * (expf(-2.f * d * d) / S5[r + 1]); }
                v = s * tr;
            }
            kb[jdx] = v;
        }
    }
}

// ---------------- conv A: 7x7 -> u,v planes. one parity per instantiation ----------------
// sub-output 64x64 per (par,b); tile = 8x8 sub-pixels; thread: o=tid&63, q=tid>>6 owns rows 2q,2q+1
template <int PY, int PX>
__global__ __launch_bounds__(256) void convA_kernel(
    const float* __restrict__ x, const float* __restrict__ ka,
    float* __restrict__ U, float* __restrict__ V)
{
    constexpr int NY = 4 - PY, NX = 4 - PX, NT = NY * NX;
    constexpr int PAR = PY * 2 + PX;
    constexpr int ROWS = 8 + NY - 1, COLS = 8 + NX - 1;
    __shared__ __align__(16) float Xs[4][ROWS][COLS];
    __shared__ __align__(16) float Ws[2][4][NT][64];
    const int tid = threadIdx.x;
    const int b = blockIdx.y;
    const int oy0 = (blockIdx.x >> 3) * 8, ox0 = (blockIdx.x & 7) * 8;
    const int o = tid & 63, q = tid >> 6;
    float acc[2][2][8];
#pragma unroll
    for (int a = 0; a < 2; ++a)
#pragma unroll
        for (int l = 0; l < 2; ++l)
#pragma unroll
            for (int c = 0; c < 8; ++c) acc[a][l][c] = 0.f;

    const float* kpar = ka + OFFA[PAR];
    for (int ic = 0; ic < 16; ++ic) {   // input channels in chunks of 4
        for (int idx = tid; idx < 4 * ROWS * COLS; idx += 256) {
            int rx = idx % COLS, t2 = idx / COLS;
            int ry = t2 % ROWS, ii = t2 / ROWS;
            int iy = oy0 - (2 - PY) + ry;
            int ix = ox0 - (2 - PX) + rx;
            float v = 0.f;
            if (iy >= 0 && iy < 64 && ix >= 0 && ix < 64)
                v = x[((b * 64 + ic * 4 + ii) * 64 + iy) * 64 + ix];
            Xs[ii][ry][rx] = v;
        }
        for (int idx = tid; idx < 2 * 4 * NT * 16; idx += 256) {
            int o4 = idx & 15, t2 = idx >> 4;
            int t = t2 % NT; t2 /= NT;
            int ii = t2 & 3, uv = t2 >> 2;
            const float4 val = *(const float4*)(kpar + ((uv * 64 + ic * 4 + ii) * NT + t) * 64 + o4 * 4);
            *(float4*)(&Ws[uv][ii][t][o4 * 4]) = val;
        }
        __syncthreads();
#pragma unroll
        for (int ii = 0; ii < 4; ++ii) {
#pragma unroll
            for (int tyi = 0; tyi < NY; ++tyi) {
                float xr0[COLS], xr1[COLS];
#pragma unroll
                for (int c2 = 0; c2 < COLS; ++c2) {
                    xr0[c2] = Xs[ii][2 * q + tyi][c2];
                    xr1[c2] = Xs[ii][2 * q + 1 + tyi][c2];
                }
#pragma unroll
                for (int txi = 0; txi < NX; ++txi) {
                    float wu = Ws[0][ii][tyi * NX + txi][o];
                    float wv = Ws[1][ii][tyi * NX + txi][o];
#pragma unroll
                    for (int c = 0; c < 8; ++c) {
                        acc[0][0][c] += wu * xr0[c + txi];
                        acc[0][1][c] += wu * xr1[c + txi];
                        acc[1][0][c] += wv * xr0[c + txi];
                        acc[1][1][c] += wv * xr1[c + txi];
                    }
                }
            }
        }
        __syncthreads();
    }
#pragma unroll
    for (int lr = 0; lr < 2; ++lr) {
        int yy = 2 * (oy0 + 2 * q + lr) + PY;
#pragma unroll
        for (int c = 0; c < 8; ++c) {
            int xx = 2 * (ox0 + c) + PX;
            int idx = ((b * 64 + o) * 128 + yy) * 128 + xx;
            U[idx] = acc[0][lr][c];
            V[idx] = acc[1][lr][c];
        }
    }
}

// ---------------- conv B: 5x5 (5 groups) + gating epilogue -> out ----------------
// tile = 4 rows x 8 cols sub-pixels; thread: o=tid&63, q=tid>>6 owns row q
template <int PY, int PX>
__global__ __launch_bounds__(256) void convB_kernel(
    const float* __restrict__ x, const float* __restrict__ kb,
    const float* __restrict__ U, const float* __restrict__ V,
    const float* __restrict__ bias, float* __restrict__ out)
{
    constexpr int NY = 2 + PY, NX = 2 + PX, NT = NY * NX;
    constexpr int PAR = PY * 2 + PX;
    constexpr int ROWS = 4 + NY - 1, COLS = 8 + NX - 1;
    __shared__ __align__(16) float Xs[4][ROWS][COLS];
    __shared__ __align__(16) float Ws[5][4][NT][64];
    const int tid = threadIdx.x;
    const int b = blockIdx.y;
    const int oy0 = (blockIdx.x >> 3) * 4, ox0 = (blockIdx.x & 7) * 8;
    const int o = tid & 63, q = tid >> 6;
    float acc[5][8];
#pragma unroll
    for (int g = 0; g < 5; ++g)
#pragma unroll
        for (int c = 0; c < 8; ++c) acc[g][c] = 0.f;

    const float* kpar = kb + OFFB[PAR];
    for (int ic = 0; ic < 16; ++ic) {
        for (int idx = tid; idx < 4 * ROWS * COLS; idx += 256) {
            int rx = idx % COLS, t2 = idx / COLS;
            int ry = t2 % ROWS, ii = t2 / ROWS;
            int iy = oy0 - 1 + ry;
            int ix = ox0 - 1 + rx;
            float v = 0.f;
            if (iy >= 0 && iy < 64 && ix >= 0 && ix < 64)
                v = x[((b * 64 + ic * 4 + ii) * 64 + iy) * 64 + ix];
            Xs[ii][ry][rx] = v;
        }
        for (int idx = tid; idx < 5 * 4 * NT * 16; idx += 256) {
            int o4 = idx & 15, t2 = idx >> 4;
            int t = t2 % NT; t2 /= NT;
            int ii = t2 & 3, g = t2 >> 2;
            const float4 val = *(const float4*)(kpar + ((g * 64 + ic * 4 + ii) * NT + t) * 64 + o4 * 4);
            *(float4*)(&Ws[g][ii][t][o4 * 4]) = val;
        }
        __syncthreads();
#pragma unroll
        for (int ii = 0; ii < 4; ++ii) {
#pragma unroll
            for (int tyi = 0; tyi < NY; ++tyi) {
                float xr[COLS];
#pragma unroll
                for (int c2 = 0; c2 < COLS; ++c2) xr[c2] = Xs[ii][q + tyi][c2];
#pragma unroll
                for (int txi = 0; txi < NX; ++txi) {
                    float wg0 = Ws[0][ii][tyi * NX + txi][o];
                    float wg1 = Ws[1][ii][tyi * NX + txi][o];
                    float wg2 = Ws[2][ii][tyi * NX + txi][o];
                    float wg3 = Ws[3][ii][tyi * NX + txi][o];
                    float wg4 = Ws[4][ii][tyi * NX + txi][o];
#pragma unroll
                    for (int c = 0; c < 8; ++c) {
                        float xv = xr[c + txi];
                        acc[0][c] += wg0 * xv;
                        acc[1][c] += wg1 * xv;
                        acc[2][c] += wg2 * xv;
                        acc[3][c] += wg3 * xv;
                        acc[4][c] += wg4 * xv;
                    }
                }
            }
        }
        __syncthreads();
    }
    const int yy = 2 * (oy0 + q) + PY;
    const float bo = bias[o];
#pragma unroll
    for (int c = 0; c < 8; ++c) {
        int xx = 2 * (ox0 + c) + PX;
        int idx = ((b * 64 + o) * 128 + yy) * 128 + xx;
        float u = U[idx], v = V[idx];
        float rho_raw = sqrtf(u * u + v * v + 1e-8f);
        float un = u / rho_raw, vn = v / rho_raw;
        float rho = tanhf(rho_raw);
        float c2v = (un - vn) * (un + vn);
        float s2v = 2.f * un * vn;
        out[idx] = acc[0][c] + rho * (un * acc[1][c] + vn * acc[2][c] + c2v * acc[3][c] + s2v * acc[4][c]) + bo;
    }
}

} // namespace

extern "C" void kernel_launch(void* const* d_in, const int* in_sizes, int n_in,
                              void* d_out, int out_size, void* d_ws, size_t ws_size,
                              hipStream_t stream)
{
    const float* x    = (const float*)d_in[0];
    const float* w0   = (const float*)d_in[1];
    const float* wc   = (const float*)d_in[2];
    const float* wsn  = (const float*)d_in[3];
    const float* wa   = (const float*)d_in[4];
    const float* bias = (const float*)d_in[5];
    float* out = (float*)d_out;

    float* wsf = (float*)d_ws;
    float* ka = wsf;
    float* kb = wsf + NKA;
    float* U  = wsf + 1048576;
    float* V  = wsf + 1048576 + 8388608;

    prep_kernel<<<dim3(512), dim3(256), 0, stream>>>(w0, wc, wsn, wa, ka, kb);

    dim3 blk(256);
    dim3 gA(64, 8);
    convA_kernel<0, 0><<<gA, blk, 0, stream>>>(x, ka, U, V);
    convA_kernel<0, 1><<<gA, blk, 0, stream>>>(x, ka, U, V);
    convA_kernel<1, 0><<<gA, blk, 0, stream>>>(x, ka, U, V);
    convA_kernel<1, 1><<<gA, blk, 0, stream>>>(x, ka, U, V);

    dim3 gB(128, 8);
    convB_kernel<0, 0><<<gB, blk, 0, stream>>>(x, kb, U, V, bias, out);
    convB_kernel<0, 1><<<gB, blk, 0, stream>>>(x, kb, U, V, bias, out);
    convB_kernel<1, 0><<<gB, blk, 0, stream>>>(x, kb, U, V, bias, out);
    convB_kernel<1, 1><<<gB, blk, 0, stream>>>(x, kb, U, V, bias, out);
}

// Round 2
// 553.320 us; speedup vs baseline: 2.4974x; 2.4974x over previous
//
#include <hip/hip_runtime.h>
#include <math.h>

// SteeredConvTranspose2d on MI355X — round 2: bf16 MFMA per-parity implicit GEMM.
//
// ws layout (bytes):
//   [0        .. 802816)    KA bf16: [e=cumtap 49][uv 2][oc 64][i 64]
//   [802816   .. 1826816)   KB bf16: [e=cumtap 25][oc 320][i 64]
//   [2097152  .. +33554432) U fp32 (8,64,128,128)
//   [35651584 .. +33554432) V fp32
// total ~66 MB.

namespace {

typedef float f4 __attribute__((ext_vector_type(4)));
typedef short s8 __attribute__((ext_vector_type(8)));

constexpr int NKA = 401408;   // 49*2*64*64
constexpr int NKB = 512000;   // 25*320*64

__device__ __forceinline__ unsigned short f2bf(float f) {
    unsigned int u = __float_as_uint(f);
    u += 0x7fffu + ((u >> 16) & 1u);
    return (unsigned short)(u >> 16);
}

// ---------------- prep: fused basis*weight -> bf16, MFMA-friendly layout ----------------
__global__ __launch_bounds__(256) void prep_kernel(
    const float* __restrict__ w0, const float* __restrict__ wc,
    const float* __restrict__ wsn, const float* __restrict__ wa,
    unsigned short* __restrict__ KA, unsigned short* __restrict__ KB,
    float sa0, float sa1, float sa2, float s50, float s51, float s52)
{
    const float SA[3] = {sa0, sa1, sa2};
    const float S5[3] = {s50, s51, s52};
    const int idx = blockIdx.x * 256 + threadIdx.x;
    if (idx < NKA) {
        int i = idx & 63;
        int e = idx >> 6;
        int oc = e & 63; e >>= 6;
        int uv = e & 1;  e >>= 1;     // e in [0,49) = cumulative tap over parities {16,12,12,9}
        int par = (e < 16) ? 0 : (e < 28) ? 1 : (e < 40) ? 2 : 3;
        int t = e - ((par == 0) ? 0 : (par == 1) ? 16 : (par == 2) ? 28 : 40);
        int py = par >> 1, px = par & 1;
        int nx = 4 - px;
        int tyi = t / nx, txi = t % nx;
        float dy = (float)(2 * tyi + py - 3), dx = (float)(2 * txi + px - 3);
        float rr = sqrtf(dy * dy + dx * dx);
        float phi = atan2f(dy, dx);
        const float* wr = wa + (oc * 64 + i) * 3;
        float v = 0.f;
#pragma unroll
        for (int r = 0; r < 3; ++r) { float d = rr - (float)(r + 1); v += wr[r] * (expf(-2.f * d * d) / SA[r]); }
        float tr = uv ? sinf(phi) : cosf(phi);
        KA[idx] = f2bf(v * tr);
    } else if (idx < NKA + NKB) {
        int j = idx - NKA;
        int i = j & 63;
        int rest = j >> 6;
        int oc = rest % 320;
        int e = rest / 320;           // [0,25) = cumulative tap over parities {4,6,6,9}
        int par = (e < 4) ? 0 : (e < 10) ? 1 : (e < 16) ? 2 : 3;
        int t = e - ((par == 0) ? 0 : (par == 1) ? 4 : (par == 2) ? 10 : 16);
        int py = par >> 1, px = par & 1;
        int nx = 2 + px;
        int tyi = t / nx, txi = t % nx;
        float dy = (float)(2 * tyi - 1 - py), dx = (float)(2 * txi - 1 - px);
        float rr = sqrtf(dy * dy + dx * dx);
        float phi = atan2f(dy, dx);
        int g = oc >> 6, o = oc & 63;
        float v = 0.f;
        if (g == 0) {
            const float* wr = w0 + (o * 64 + i) * 3;
#pragma unroll
            for (int r = 0; r < 3; ++r) { float d = rr - (float)r; v += wr[r] * (expf(-2.f * d * d) / S5[r]); }
        } else {
            int k = (g - 1) >> 1, sn = (g - 1) & 1;
            const float* wsel = ((sn == 0) ? wc : wsn) + ((k * 64 + o) * 64 + i) * 2;
            float s = 0.f;
#pragma unroll
            for (int r = 0; r < 2; ++r) { float d = rr - (float)(r + 1); s += wsel[r] * (expf(-2.f * d * d) / S5[r + 1]); }
            float ang = (float)(k + 1) * phi;
            v = s * ((sn == 0) ? cosf(ang) : sinf(ang));
        }
        KB[j] = f2bf(v);
    }
}

// ---------------- conv A (7x7 taps) -> U,V fp32 planes ----------------
// WG=256thr=4 waves; covers (b, oy): M=128 oc (u,v) x N=64 px, K=64*NT.
// wave: mc=w&1 selects u/v plane (64 oc), nc=w>>1 selects 32-px half.
template <int PY, int PX>
__global__ __launch_bounds__(256, 2) void convA_mfma(
    const float* __restrict__ x, const unsigned short* __restrict__ KA,
    float* __restrict__ U, float* __restrict__ V)
{
    constexpr int NY = 4 - PY, NX = 4 - PX, NT = NY * NX, COLS = 64 + NX - 1;
    constexpr int PAR = 2 * PY + PX;
    constexpr int TB = (PAR == 0) ? 0 : (PAR == 1) ? 16 : (PAR == 2) ? 28 : 40;
    __shared__ unsigned short Xs[NY * COLS * 64];
    const int tid = threadIdx.x;
    const int oy = blockIdx.x, b = blockIdx.y;

    // stage X tile: [row][rx][ch] bf16 with 16B-granule XOR swizzle on ch
    {
        const int ixl = tid & 63, chb = tid >> 6;
        for (int r = 0; r < NY; ++r) {
            const int iy = oy - (2 - PY) + r;
            for (int cc = 0; cc < 2; ++cc) {
                const int rx = cc * 64 + ixl;
                if (rx < COLS) {
                    const int ix = rx - (2 - PX);
                    const bool ok = (iy >= 0) & (iy < 64) & (ix >= 0) & (ix < 64);
#pragma unroll
                    for (int ii = 0; ii < 16; ++ii) {
                        const int ch = ii * 4 + chb;
                        float v = 0.f;
                        if (ok) v = x[((b * 64 + ch) * 64 + iy) * 64 + ix];
                        const int gz = (ch >> 3) ^ (rx & 7);
                        Xs[(r * COLS + rx) * 64 + gz * 8 + (ch & 7)] = f2bf(v);
                    }
                }
            }
        }
    }
    __syncthreads();

    const int lane = tid & 63, lr = lane & 15, hi = lane >> 4;
    const int w = tid >> 6, mc = w & 1, nc = w >> 1;
    const unsigned short* wb = KA + TB * 8192 + mc * 4096;

    f4 acc[4][2];
#pragma unroll
    for (int mi = 0; mi < 4; ++mi)
#pragma unroll
        for (int ni = 0; ni < 2; ++ni) acc[mi][ni] = f4{0.f, 0.f, 0.f, 0.f};

#pragma unroll
    for (int t = 0; t < NT; ++t) {
        const int tyi = t / NX, txi = t % NX;
        const unsigned short* wt = wb + t * 8192;
#pragma unroll
        for (int ks = 0; ks < 2; ++ks) {
            s8 a[4], bf[2];
#pragma unroll
            for (int mi = 0; mi < 4; ++mi)
                a[mi] = *(const s8*)(wt + (mi * 16 + lr) * 64 + ks * 32 + hi * 8);
#pragma unroll
            for (int ni = 0; ni < 2; ++ni) {
                const int rx = nc * 32 + ni * 16 + lr + txi;
                const int gz = (ks * 4 + hi) ^ (rx & 7);
                bf[ni] = *(const s8*)(&Xs[(tyi * COLS + rx) * 64 + gz * 8]);
            }
#pragma unroll
            for (int mi = 0; mi < 4; ++mi)
#pragma unroll
                for (int ni = 0; ni < 2; ++ni)
                    acc[mi][ni] = __builtin_amdgcn_mfma_f32_16x16x32_bf16(a[mi], bf[ni], acc[mi][ni], 0, 0, 0);
        }
    }

    float* dst = mc ? V : U;
    const int yy = 2 * oy + PY;
#pragma unroll
    for (int mi = 0; mi < 4; ++mi)
#pragma unroll
        for (int ni = 0; ni < 2; ++ni)
#pragma unroll
            for (int r2 = 0; r2 < 4; ++r2) {
                const int ch = mi * 16 + hi * 4 + r2;
                const int px = nc * 32 + ni * 16 + lr;
                dst[((b * 64 + ch) * 128 + yy) * 128 + 2 * px + PX] = acc[mi][ni][r2];
            }
}

// ---------------- conv B (5x5 taps, 5 groups) + gating epilogue -> out ----------------
// WG=256thr=4 waves; covers (b, oy): M=320 oc x N=64 px.
// wave: mc=w&1 selects o-half [mc*32,+32) across all 5 groups (10 m-frags), nc=w>>1 px half.
template <int PY, int PX>
__global__ __launch_bounds__(256, 2) void convB_mfma(
    const float* __restrict__ x, const unsigned short* __restrict__ KB,
    const float* __restrict__ U, const float* __restrict__ V,
    const float* __restrict__ bias, float* __restrict__ out)
{
    constexpr int NY = 2 + PY, NX = 2 + PX, NT = NY * NX, COLS = 64 + NX - 1;
    constexpr int PAR = 2 * PY + PX;
    constexpr int TB = (PAR == 0) ? 0 : (PAR == 1) ? 4 : (PAR == 2) ? 10 : 16;
    __shared__ unsigned short Xs[NY * COLS * 64];
    const int tid = threadIdx.x;
    const int oy = blockIdx.x, b = blockIdx.y;

    {
        const int ixl = tid & 63, chb = tid >> 6;
        for (int r = 0; r < NY; ++r) {
            const int iy = oy - 1 + r;
            for (int cc = 0; cc < 2; ++cc) {
                const int rx = cc * 64 + ixl;
                if (rx < COLS) {
                    const int ix = rx - 1;
                    const bool ok = (iy >= 0) & (iy < 64) & (ix >= 0) & (ix < 64);
#pragma unroll
                    for (int ii = 0; ii < 16; ++ii) {
                        const int ch = ii * 4 + chb;
                        float v = 0.f;
                        if (ok) v = x[((b * 64 + ch) * 64 + iy) * 64 + ix];
                        const int gz = (ch >> 3) ^ (rx & 7);
                        Xs[(r * COLS + rx) * 64 + gz * 8 + (ch & 7)] = f2bf(v);
                    }
                }
            }
        }
    }
    __syncthreads();

    const int lane = tid & 63, lr = lane & 15, hi = lane >> 4;
    const int w = tid >> 6, mc = w & 1, nc = w >> 1;
    const unsigned short* wb = KB + TB * 20480;

    f4 acc[5][2][2];
#pragma unroll
    for (int g = 0; g < 5; ++g)
#pragma unroll
        for (int mo = 0; mo < 2; ++mo)
#pragma unroll
            for (int ni = 0; ni < 2; ++ni) acc[g][mo][ni] = f4{0.f, 0.f, 0.f, 0.f};

#pragma unroll
    for (int t = 0; t < NT; ++t) {
        const int tyi = t / NX, txi = t % NX;
        const unsigned short* wt = wb + t * 20480;
#pragma unroll
        for (int ks = 0; ks < 2; ++ks) {
            s8 a[5][2], bf[2];
#pragma unroll
            for (int g = 0; g < 5; ++g)
#pragma unroll
                for (int mo = 0; mo < 2; ++mo)
                    a[g][mo] = *(const s8*)(wt + (g * 64 + mc * 32 + mo * 16 + lr) * 64 + ks * 32 + hi * 8);
#pragma unroll
            for (int ni = 0; ni < 2; ++ni) {
                const int rx = nc * 32 + ni * 16 + lr + txi;
                const int gz = (ks * 4 + hi) ^ (rx & 7);
                bf[ni] = *(const s8*)(&Xs[(tyi * COLS + rx) * 64 + gz * 8]);
            }
#pragma unroll
            for (int g = 0; g < 5; ++g)
#pragma unroll
                for (int mo = 0; mo < 2; ++mo)
#pragma unroll
                    for (int ni = 0; ni < 2; ++ni)
                        acc[g][mo][ni] = __builtin_amdgcn_mfma_f32_16x16x32_bf16(a[g][mo], bf[ni], acc[g][mo][ni], 0, 0, 0);
        }
    }

    const int yy = 2 * oy + PY;
#pragma unroll
    for (int mo = 0; mo < 2; ++mo)
#pragma unroll
        for (int ni = 0; ni < 2; ++ni)
#pragma unroll
            for (int r2 = 0; r2 < 4; ++r2) {
                const int o = mc * 32 + mo * 16 + hi * 4 + r2;
                const int px = nc * 32 + ni * 16 + lr;
                const int xx = 2 * px + PX;
                const int idx = ((b * 64 + o) * 128 + yy) * 128 + xx;
                const float u = U[idx], v = V[idx];
                const float rho_raw = sqrtf(u * u + v * v + 1e-8f);
                const float un = u / rho_raw, vn = v / rho_raw;
                const float rho = tanhf(rho_raw);
                const float c2 = (un - vn) * (un + vn);
                const float sp = 2.f * un * vn;
                out[idx] = acc[0][mo][ni][r2]
                         + rho * (un * acc[1][mo][ni][r2] + vn * acc[2][mo][ni][r2]
                                + c2 * acc[3][mo][ni][r2] + sp * acc[4][mo][ni][r2])
                         + bias[o];
            }
}

} // namespace

extern "C" void kernel_launch(void* const* d_in, const int* in_sizes, int n_in,
                              void* d_out, int out_size, void* d_ws, size_t ws_size,
                              hipStream_t stream)
{
    const float* x    = (const float*)d_in[0];
    const float* w0   = (const float*)d_in[1];
    const float* wc   = (const float*)d_in[2];
    const float* wsn  = (const float*)d_in[3];
    const float* wa   = (const float*)d_in[4];
    const float* bias = (const float*)d_in[5];
    float* out = (float*)d_out;

    char* wsb = (char*)d_ws;
    unsigned short* KA = (unsigned short*)(wsb);
    unsigned short* KB = (unsigned short*)(wsb + 802816);
    float* U = (float*)(wsb + 2097152);
    float* V = (float*)(wsb + 35651584);

    // host-side radial normalization constants (pure CPU math, capture-safe)
    float SA[3] = {0.f, 0.f, 0.f}, S5[3] = {0.f, 0.f, 0.f};
    for (int ky = 0; ky < 7; ++ky)
        for (int kx = 0; kx < 7; ++kx) {
            float dy = (float)(ky - 3), dx = (float)(kx - 3);
            float rr = sqrtf(dy * dy + dx * dx);
            for (int r = 0; r < 3; ++r) { float d = rr - (float)(r + 1); SA[r] += expf(-2.f * d * d); }
        }
    for (int ky = 0; ky < 5; ++ky)
        for (int kx = 0; kx < 5; ++kx) {
            float dy = (float)(ky - 2), dx = (float)(kx - 2);
            float rr = sqrtf(dy * dy + dx * dx);
            for (int r = 0; r < 3; ++r) { float d = rr - (float)r; S5[r] += expf(-2.f * d * d); }
        }

    prep_kernel<<<dim3(3568), dim3(256), 0, stream>>>(w0, wc, wsn, wa, KA, KB,
                                                      SA[0], SA[1], SA[2], S5[0], S5[1], S5[2]);

    dim3 blk(256);
    dim3 g(64, 8);
    convA_mfma<0, 0><<<g, blk, 0, stream>>>(x, KA, U, V);
    convA_mfma<0, 1><<<g, blk, 0, stream>>>(x, KA, U, V);
    convA_mfma<1, 0><<<g, blk, 0, stream>>>(x, KA, U, V);
    convA_mfma<1, 1><<<g, blk, 0, stream>>>(x, KA, U, V);

    convB_mfma<0, 0><<<g, blk, 0, stream>>>(x, KB, U, V, bias, out);
    convB_mfma<0, 1><<<g, blk, 0, stream>>>(x, KB, U, V, bias, out);
    convB_mfma<1, 0><<<g, blk, 0, stream>>>(x, KB, U, V, bias, out);
    convB_mfma<1, 1><<<g, blk, 0, stream>>>(x, KB, U, V, bias, out);
}

// Round 3
// 318.533 us; speedup vs baseline: 4.3382x; 1.7371x over previous
//
#include <hip/hip_runtime.h>
#include <math.h>

// SteeredConvTranspose2d on MI355X — round 3: single fused bf16-MFMA kernel.
// conv7x7(u,v) + conv5x5(5 groups) + gating epilogue fused per parity class;
// all 4 parities in one dispatch (blockIdx.z).
//
// ws layout (bytes):
//   [0       .. 802816)   KA bf16: [e=cumtap 49][uv 2][oc 64][i 64]
//   [802816  .. 1826816)  KB bf16: [e=cumtap 25][oc 320][i 64]

namespace {

typedef float f4 __attribute__((ext_vector_type(4)));
typedef short s8 __attribute__((ext_vector_type(8)));

constexpr int NKA = 401408;   // 49*2*64*64
constexpr int NKB = 512000;   // 25*320*64

__device__ __forceinline__ unsigned short f2bf(float f) {
    unsigned int u = __float_as_uint(f);
    u += 0x7fffu + ((u >> 16) & 1u);
    return (unsigned short)(u >> 16);
}

// ---------------- prep: fused basis*weight -> bf16, MFMA-friendly layout ----------------
__global__ __launch_bounds__(256) void prep_kernel(
    const float* __restrict__ w0, const float* __restrict__ wc,
    const float* __restrict__ wsn, const float* __restrict__ wa,
    unsigned short* __restrict__ KA, unsigned short* __restrict__ KB,
    float sa0, float sa1, float sa2, float s50, float s51, float s52)
{
    const float SA[3] = {sa0, sa1, sa2};
    const float S5[3] = {s50, s51, s52};
    const int idx = blockIdx.x * 256 + threadIdx.x;
    if (idx < NKA) {
        int i = idx & 63;
        int e = idx >> 6;
        int oc = e & 63; e >>= 6;
        int uv = e & 1;  e >>= 1;     // e in [0,49) cumulative tap over parities {16,12,12,9}
        int par = (e < 16) ? 0 : (e < 28) ? 1 : (e < 40) ? 2 : 3;
        int t = e - ((par == 0) ? 0 : (par == 1) ? 16 : (par == 2) ? 28 : 40);
        int py = par >> 1, px = par & 1;
        int nx = 4 - px;
        int tyi = t / nx, txi = t % nx;
        float dy = (float)(2 * tyi + py - 3), dx = (float)(2 * txi + px - 3);
        float rr = sqrtf(dy * dy + dx * dx);
        float phi = atan2f(dy, dx);
        const float* wr = wa + (oc * 64 + i) * 3;
        float v = 0.f;
#pragma unroll
        for (int r = 0; r < 3; ++r) { float d = rr - (float)(r + 1); v += wr[r] * (expf(-2.f * d * d) / SA[r]); }
        float tr = uv ? sinf(phi) : cosf(phi);
        KA[idx] = f2bf(v * tr);
    } else if (idx < NKA + NKB) {
        int j = idx - NKA;
        int i = j & 63;
        int rest = j >> 6;
        int oc = rest % 320;
        int e = rest / 320;           // [0,25) cumulative tap over parities {4,6,6,9}
        int par = (e < 4) ? 0 : (e < 10) ? 1 : (e < 16) ? 2 : 3;
        int t = e - ((par == 0) ? 0 : (par == 1) ? 4 : (par == 2) ? 10 : 16);
        int py = par >> 1, px = par & 1;
        int nx = 2 + px;
        int tyi = t / nx, txi = t % nx;
        float dy = (float)(2 * tyi - 1 - py), dx = (float)(2 * txi - 1 - px);
        float rr = sqrtf(dy * dy + dx * dx);
        float phi = atan2f(dy, dx);
        int g = oc >> 6, o = oc & 63;
        float v = 0.f;
        if (g == 0) {
            const float* wr = w0 + (o * 64 + i) * 3;
#pragma unroll
            for (int r = 0; r < 3; ++r) { float d = rr - (float)r; v += wr[r] * (expf(-2.f * d * d) / S5[r]); }
        } else {
            int k = (g - 1) >> 1, sn = (g - 1) & 1;
            const float* wsel = ((sn == 0) ? wc : wsn) + ((k * 64 + o) * 64 + i) * 2;
            float s = 0.f;
#pragma unroll
            for (int r = 0; r < 2; ++r) { float d = rr - (float)(r + 1); s += wsel[r] * (expf(-2.f * d * d) / S5[r + 1]); }
            float ang = (float)(k + 1) * phi;
            v = s * ((sn == 0) ? cosf(ang) : sinf(ang));
        }
        KB[j] = f2bf(v);
    }
}

// ---------------- fused conv body, one parity ----------------
// WG = 512 thr = 8 waves, covers (b, oy) -> output row yy=2oy+PY, 64 px (xx=2px+PX).
// wave: mq = w&3 -> o in [mq*16, mq*16+16) across all 7 chunks {u,v,g0..g4};
//       nc = w>>2 -> px half [nc*32, +32), 2 n-frags.
// X tile staged once in LDS (covers both 7x7 and 5x5 tap windows);
// weights read directly from L2 (KA/KB ~1.8 MB resident).
template <int PY, int PX>
__device__ __forceinline__ void fused_body(
    const float* __restrict__ x, const unsigned short* __restrict__ KA,
    const unsigned short* __restrict__ KB, const float* __restrict__ bias,
    float* __restrict__ out, unsigned short* Xs)
{
    constexpr int NXA = 4 - PX, NYA = 4 - PY, NTA = NYA * NXA;
    constexpr int NXB = 2 + PX, NYB = 2 + PY, NTB = NYB * NXB;
    constexpr int PAR = 2 * PY + PX;
    constexpr int TBA = (PAR == 0) ? 0 : (PAR == 1) ? 16 : (PAR == 2) ? 28 : 40;
    constexpr int TBB = (PAR == 0) ? 0 : (PAR == 1) ? 4  : (PAR == 2) ? 10 : 16;
    constexpr int COLSV = 67 - PX;   // valid cols; physical row stride fixed at 67

    const int tid = threadIdx.x;
    const int oy = blockIdx.x, b = blockIdx.y;

    // ---- stage X tile: [row<NYA][rx][ch 64] bf16, 16B-granule XOR swizzle on ch ----
    {
        const int ixl = tid & 63, chb = (tid >> 6) & 7;
        for (int r = 0; r < NYA; ++r) {
            const int iy = oy - (2 - PY) + r;
            for (int cc = 0; cc < 2; ++cc) {
                const int rx = cc * 64 + ixl;
                if (rx < COLSV) {
                    const int ix = rx - (2 - PX);
                    const bool ok = (iy >= 0) & (iy < 64) & (ix >= 0) & (ix < 64);
#pragma unroll
                    for (int ii = 0; ii < 8; ++ii) {
                        const int ch = ii * 8 + chb;
                        float v = ok ? x[((b * 64 + ch) * 64 + iy) * 64 + ix] : 0.f;
                        const int gz = ii ^ (rx & 7);
                        Xs[(r * 67 + rx) * 64 + gz * 8 + chb] = f2bf(v);
                    }
                }
            }
        }
    }
    __syncthreads();

    const int lane = tid & 63, lr = lane & 15, hi = lane >> 4;
    const int w = tid >> 6;
    const int mq = w & 3, nc = w >> 2;

    f4 accA[2][2];
    f4 accB[5][2];
#pragma unroll
    for (int uv = 0; uv < 2; ++uv)
#pragma unroll
        for (int ni = 0; ni < 2; ++ni) accA[uv][ni] = f4{0.f, 0.f, 0.f, 0.f};
#pragma unroll
    for (int g = 0; g < 5; ++g)
#pragma unroll
        for (int ni = 0; ni < 2; ++ni) accB[g][ni] = f4{0.f, 0.f, 0.f, 0.f};

    // ---- phase A: 7x7 taps -> u,v ----
#pragma unroll
    for (int t = 0; t < NTA; ++t) {
        const int tyi = t / NXA, txi = t % NXA;
#pragma unroll
        for (int ks = 0; ks < 2; ++ks) {
            s8 a[2];
#pragma unroll
            for (int uv = 0; uv < 2; ++uv)
                a[uv] = *(const s8*)(KA + (((TBA + t) * 2 + uv) * 64 + mq * 16 + lr) * 64 + ks * 32 + hi * 8);
            s8 bfr[2];
#pragma unroll
            for (int ni = 0; ni < 2; ++ni) {
                const int rx = nc * 32 + ni * 16 + lr + txi;
                const int gz = (ks * 4 + hi) ^ (rx & 7);
                bfr[ni] = *(const s8*)(Xs + (tyi * 67 + rx) * 64 + gz * 8);
            }
#pragma unroll
            for (int uv = 0; uv < 2; ++uv)
#pragma unroll
                for (int ni = 0; ni < 2; ++ni)
                    accA[uv][ni] = __builtin_amdgcn_mfma_f32_16x16x32_bf16(a[uv], bfr[ni], accA[uv][ni], 0, 0, 0);
        }
    }

    // ---- phase B: 5x5 taps -> 5 groups (same LDS tile, offset rows/cols) ----
#pragma unroll
    for (int t = 0; t < NTB; ++t) {
        const int tyi = t / NXB, txi = t % NXB;
        const int row = tyi + (1 - PY);
        const int rxo = txi + (1 - PX);
#pragma unroll
        for (int ks = 0; ks < 2; ++ks) {
            s8 a[5];
#pragma unroll
            for (int g = 0; g < 5; ++g)
                a[g] = *(const s8*)(KB + ((TBB + t) * 320 + g * 64 + mq * 16 + lr) * 64 + ks * 32 + hi * 8);
            s8 bfr[2];
#pragma unroll
            for (int ni = 0; ni < 2; ++ni) {
                const int rx = nc * 32 + ni * 16 + lr + rxo;
                const int gz = (ks * 4 + hi) ^ (rx & 7);
                bfr[ni] = *(const s8*)(Xs + (row * 67 + rx) * 64 + gz * 8);
            }
#pragma unroll
            for (int g = 0; g < 5; ++g)
#pragma unroll
                for (int ni = 0; ni < 2; ++ni)
                    accB[g][ni] = __builtin_amdgcn_mfma_f32_16x16x32_bf16(a[g], bfr[ni], accB[g][ni], 0, 0, 0);
        }
    }

    // ---- epilogue: gating + bias, all lane-local ----
    const int yy = 2 * oy + PY;
#pragma unroll
    for (int ni = 0; ni < 2; ++ni) {
        const int px = nc * 32 + ni * 16 + lr;
        const int xx = 2 * px + PX;
#pragma unroll
        for (int r2 = 0; r2 < 4; ++r2) {
            const int o = mq * 16 + hi * 4 + r2;
            const float u = accA[0][ni][r2], v = accA[1][ni][r2];
            const float rho_raw = sqrtf(u * u + v * v + 1e-8f);
            const float un = u / rho_raw, vn = v / rho_raw;
            const float rho = tanhf(rho_raw);
            const float c2 = (un - vn) * (un + vn);
            const float sp = 2.f * un * vn;
            out[((b * 64 + o) * 128 + yy) * 128 + xx] =
                accB[0][ni][r2]
                + rho * (un * accB[1][ni][r2] + vn * accB[2][ni][r2]
                       + c2 * accB[3][ni][r2] + sp * accB[4][ni][r2])
                + bias[o];
        }
    }
}

__global__ __launch_bounds__(512, 4) void fused_kernel(
    const float* __restrict__ x, const unsigned short* __restrict__ KA,
    const unsigned short* __restrict__ KB, const float* __restrict__ bias,
    float* __restrict__ out)
{
    __shared__ unsigned short Xs[4 * 67 * 64];
    switch (blockIdx.z) {
        case 0: fused_body<0, 0>(x, KA, KB, bias, out, Xs); break;
        case 1: fused_body<0, 1>(x, KA, KB, bias, out, Xs); break;
        case 2: fused_body<1, 0>(x, KA, KB, bias, out, Xs); break;
        default: fused_body<1, 1>(x, KA, KB, bias, out, Xs); break;
    }
}

} // namespace

extern "C" void kernel_launch(void* const* d_in, const int* in_sizes, int n_in,
                              void* d_out, int out_size, void* d_ws, size_t ws_size,
                              hipStream_t stream)
{
    const float* x    = (const float*)d_in[0];
    const float* w0   = (const float*)d_in[1];
    const float* wc   = (const float*)d_in[2];
    const float* wsn  = (const float*)d_in[3];
    const float* wa   = (const float*)d_in[4];
    const float* bias = (const float*)d_in[5];
    float* out = (float*)d_out;

    char* wsb = (char*)d_ws;
    unsigned short* KA = (unsigned short*)(wsb);
    unsigned short* KB = (unsigned short*)(wsb + 802816);

    // host-side radial normalization constants (pure CPU math, capture-safe)
    float SA[3] = {0.f, 0.f, 0.f}, S5[3] = {0.f, 0.f, 0.f};
    for (int ky = 0; ky < 7; ++ky)
        for (int kx = 0; kx < 7; ++kx) {
            float dy = (float)(ky - 3), dx = (float)(kx - 3);
            float rr = sqrtf(dy * dy + dx * dx);
            for (int r = 0; r < 3; ++r) { float d = rr - (float)(r + 1); SA[r] += expf(-2.f * d * d); }
        }
    for (int ky = 0; ky < 5; ++ky)
        for (int kx = 0; kx < 5; ++kx) {
            float dy = (float)(ky - 2), dx = (float)(kx - 2);
            float rr = sqrtf(dy * dy + dx * dx);
            for (int r = 0; r < 3; ++r) { float d = rr - (float)r; S5[r] += expf(-2.f * d * d); }
        }

    prep_kernel<<<dim3(3568), dim3(256), 0, stream>>>(w0, wc, wsn, wa, KA, KB,
                                                      SA[0], SA[1], SA[2], S5[0], S5[1], S5[2]);

    fused_kernel<<<dim3(64, 8, 4), dim3(512), 0, stream>>>(x, KA, KB, bias, out);
}

// Round 4
// 235.311 us; speedup vs baseline: 5.8725x; 1.3537x over previous
//
#include <hip/hip_runtime.h>
#include <math.h>

// SteeredConvTranspose2d on MI355X — round 4.
// prep (weights*basis -> bf16) ; transpose+pad x -> Xt bf16 [b][68][68][64] ;
// fused conv: per (oy,b,PY,oh): waves = (PX parity, o-quarter), 7x7-and-5x5
// taps share LDS B-frags (5x5 window subset of 7x7 window), epilogue in-reg.
//
// ws layout (bytes):
//   [0       .. 802816)    KA bf16 [e 49][uv 2][oc 64][i 64]
//   [802816  .. 1826816)   KB bf16 [e 25][oc 320][i 64]
//   [2097152 .. +4734976)  Xt bf16 [8][68][68][64]  (zero-padded halo)

namespace {

typedef float f4 __attribute__((ext_vector_type(4)));
typedef short s8 __attribute__((ext_vector_type(8)));

constexpr int NKA = 401408;   // 49*2*64*64
constexpr int NKB = 512000;   // 25*320*64

__device__ __forceinline__ unsigned short f2bf(float f) {
    unsigned int u = __float_as_uint(f);
    u += 0x7fffu + ((u >> 16) & 1u);
    return (unsigned short)(u >> 16);
}

// ---------------- prep: fused basis*weight -> bf16 ----------------
__global__ __launch_bounds__(256) void prep_kernel(
    const float* __restrict__ w0, const float* __restrict__ wc,
    const float* __restrict__ wsn, const float* __restrict__ wa,
    unsigned short* __restrict__ KA, unsigned short* __restrict__ KB,
    float sa0, float sa1, float sa2, float s50, float s51, float s52)
{
    const float SA[3] = {sa0, sa1, sa2};
    const float S5[3] = {s50, s51, s52};
    const int idx = blockIdx.x * 256 + threadIdx.x;
    if (idx < NKA) {
        int i = idx & 63;
        int e = idx >> 6;
        int oc = e & 63; e >>= 6;
        int uv = e & 1;  e >>= 1;     // e in [0,49) cumulative tap over parities {16,12,12,9}
        int par = (e < 16) ? 0 : (e < 28) ? 1 : (e < 40) ? 2 : 3;
        int t = e - ((par == 0) ? 0 : (par == 1) ? 16 : (par == 2) ? 28 : 40);
        int py = par >> 1, px = par & 1;
        int nx = 4 - px;
        int tyi = t / nx, txi = t % nx;
        float dy = (float)(2 * tyi + py - 3), dx = (float)(2 * txi + px - 3);
        float rr = sqrtf(dy * dy + dx * dx);
        float phi = atan2f(dy, dx);
        const float* wr = wa + (oc * 64 + i) * 3;
        float v = 0.f;
#pragma unroll
        for (int r = 0; r < 3; ++r) { float d = rr - (float)(r + 1); v += wr[r] * (expf(-2.f * d * d) / SA[r]); }
        float tr = uv ? sinf(phi) : cosf(phi);
        KA[idx] = f2bf(v * tr);
    } else if (idx < NKA + NKB) {
        int j = idx - NKA;
        int i = j & 63;
        int rest = j >> 6;
        int oc = rest % 320;
        int e = rest / 320;           // [0,25) cumulative tap over parities {4,6,6,9}
        int par = (e < 4) ? 0 : (e < 10) ? 1 : (e < 16) ? 2 : 3;
        int t = e - ((par == 0) ? 0 : (par == 1) ? 4 : (par == 2) ? 10 : 16);
        int py = par >> 1, px = par & 1;
        int nx = 2 + px;
        int tyi = t / nx, txi = t % nx;
        float dy = (float)(2 * tyi - 1 - py), dx = (float)(2 * txi - 1 - px);
        float rr = sqrtf(dy * dy + dx * dx);
        float phi = atan2f(dy, dx);
        int g = oc >> 6, o = oc & 63;
        float v = 0.f;
        if (g == 0) {
            const float* wr = w0 + (o * 64 + i) * 3;
#pragma unroll
            for (int r = 0; r < 3; ++r) { float d = rr - (float)r; v += wr[r] * (expf(-2.f * d * d) / S5[r]); }
        } else {
            int k = (g - 1) >> 1, sn = (g - 1) & 1;
            const float* wsel = ((sn == 0) ? wc : wsn) + ((k * 64 + o) * 64 + i) * 2;
            float s = 0.f;
#pragma unroll
            for (int r = 0; r < 2; ++r) { float d = rr - (float)(r + 1); s += wsel[r] * (expf(-2.f * d * d) / S5[r + 1]); }
            float ang = (float)(k + 1) * phi;
            v = s * ((sn == 0) ? cosf(ang) : sinf(ang));
        }
        KB[j] = f2bf(v);
    }
}

// ---------------- transpose+pad: x fp32 NCHW -> Xt bf16 [b][iyp 68][ixp 68][ch 64] ----------------
__global__ __launch_bounds__(256) void transpose_kernel(
    const float* __restrict__ x, unsigned short* __restrict__ Xt)
{
    __shared__ float LF[64][65];
    const int t = threadIdx.x;
    const int iyp = blockIdx.x, b = blockIdx.y;
    const int iy = iyp - 2;
    unsigned int* Xtu = (unsigned int*)(Xt + (size_t)(b * 68 + iyp) * 68 * 64);
    if (iy < 0 || iy >= 64) {
        for (int k = t; k < 68 * 32; k += 256) Xtu[k] = 0u;
        return;
    }
    const float* xb = x + (size_t)b * 262144 + iy * 64;
#pragma unroll
    for (int it = 0; it < 16; ++it) {
        int ch = it * 4 + (t >> 6);
        LF[ch][t & 63] = xb[(size_t)ch * 4096 + (t & 63)];
    }
    __syncthreads();
    if (t < 128) {   // zero border cols ixp in {0,1,66,67}
        int colidx = t >> 5;
        int ixp = (colidx < 2) ? colidx : 64 + colidx;
        Xtu[ixp * 32 + (t & 31)] = 0u;
    }
    const int lane = t & 63, w = t >> 6;
#pragma unroll
    for (int k = 0; k < 8; ++k) {
        int it = w * 8 + k;                 // 0..31
        int ix = 2 * it + (lane >> 5);      // 0..63
        int ch = 2 * (lane & 31);
        unsigned int pack = (unsigned int)f2bf(LF[ch][ix]) | ((unsigned int)f2bf(LF[ch + 1][ix]) << 16);
        Xtu[(ix + 2) * 32 + (lane & 31)] = pack;
    }
}

// ---------------- fused conv: MFMA loop for one (PY, PX) wave ----------------
template <int PY, int PX>
__device__ __forceinline__ void mfma_loop(
    const unsigned short* __restrict__ Xs,
    const unsigned short* __restrict__ KA, const unsigned short* __restrict__ KB,
    const float* __restrict__ bias, float* __restrict__ out,
    int b, int oy, int obase, int lr, int hi)
{
    constexpr int NXA = 4 - PX, NYA = 4 - PY, NTA = NYA * NXA;
    constexpr int NXB = 2 + PX, NYB = 2 + PY;
    constexpr int PAR = 2 * PY + PX;
    constexpr int TBA = (PAR == 0) ? 0 : (PAR == 1) ? 16 : (PAR == 2) ? 28 : 40;
    constexpr int TBB = (PAR == 0) ? 0 : (PAR == 1) ? 4  : (PAR == 2) ? 10 : 16;

    f4 accA[2][4];
    f4 accB[5][4];
#pragma unroll
    for (int uv = 0; uv < 2; ++uv)
#pragma unroll
        for (int ni = 0; ni < 4; ++ni) accA[uv][ni] = f4{0.f, 0.f, 0.f, 0.f};
#pragma unroll
    for (int g = 0; g < 5; ++g)
#pragma unroll
        for (int ni = 0; ni < 4; ++ni) accB[g][ni] = f4{0.f, 0.f, 0.f, 0.f};

#pragma unroll
    for (int tA = 0; tA < NTA; ++tA) {
        const int tyi = tA / NXA, txi = tA % NXA;
        const int tyiB = tyi - (1 - PY), txiB = txi - (1 - PX);
        const bool bval = (tyiB >= 0) && (tyiB < NYB) && (txiB >= 0) && (txiB < NXB);
#pragma unroll
        for (int ks = 0; ks < 2; ++ks) {
            s8 bfr[4];
#pragma unroll
            for (int ni = 0; ni < 4; ++ni) {
                const int rx = ni * 16 + lr + txi + PX;
                const int gz = (ks * 4 + hi) ^ (rx & 7);
                bfr[ni] = *(const s8*)(Xs + ((tyi * 68 + rx) * 8 + gz) * 8);
            }
            {
                s8 aA[2];
#pragma unroll
                for (int uv = 0; uv < 2; ++uv)
                    aA[uv] = *(const s8*)(KA + (((TBA + tA) * 2 + uv) * 64 + obase + lr) * 64 + ks * 32 + hi * 8);
#pragma unroll
                for (int uv = 0; uv < 2; ++uv)
#pragma unroll
                    for (int ni = 0; ni < 4; ++ni)
                        accA[uv][ni] = __builtin_amdgcn_mfma_f32_16x16x32_bf16(aA[uv], bfr[ni], accA[uv][ni], 0, 0, 0);
            }
            if (bval) {
                const int tB = tyiB * NXB + txiB;
                s8 aB[5];
#pragma unroll
                for (int g = 0; g < 5; ++g)
                    aB[g] = *(const s8*)(KB + ((TBB + tB) * 320 + g * 64 + obase + lr) * 64 + ks * 32 + hi * 8);
#pragma unroll
                for (int g = 0; g < 5; ++g)
#pragma unroll
                    for (int ni = 0; ni < 4; ++ni)
                        accB[g][ni] = __builtin_amdgcn_mfma_f32_16x16x32_bf16(aB[g], bfr[ni], accB[g][ni], 0, 0, 0);
            }
        }
    }

    // epilogue: gating + bias
    const int yy = 2 * oy + PY;
#pragma unroll
    for (int ni = 0; ni < 4; ++ni) {
        const int px = ni * 16 + lr;
        const int xx = 2 * px + PX;
#pragma unroll
        for (int r2 = 0; r2 < 4; ++r2) {
            const int o = obase + hi * 4 + r2;
            const float u = accA[0][ni][r2], v = accA[1][ni][r2];
            const float rho_raw = sqrtf(u * u + v * v + 1e-8f);
            const float un = u / rho_raw, vn = v / rho_raw;
            const float rho = tanhf(rho_raw);
            const float c2 = (un - vn) * (un + vn);
            const float sp = 2.f * un * vn;
            out[((b * 64 + o) * 128 + yy) * 128 + xx] =
                accB[0][ni][r2]
                + rho * (un * accB[1][ni][r2] + vn * accB[2][ni][r2]
                       + c2 * accB[3][ni][r2] + sp * accB[4][ni][r2])
                + bias[o];
        }
    }
}

template <int PY>
__device__ __forceinline__ void fused_body(
    const unsigned short* __restrict__ Xt,
    const unsigned short* __restrict__ KA, const unsigned short* __restrict__ KB,
    const float* __restrict__ bias, float* __restrict__ out,
    int oh, unsigned short* Xs)
{
    constexpr int NYA = 4 - PY;
    const int tid = threadIdx.x;
    const int oy = blockIdx.x, b = blockIdx.y;

    // ---- stage NYA rows of Xt into LDS (granule = 16B = 8ch), XOR pre-swizzle on source ----
    {
        const int iy0 = oy - (2 - PY);
        const unsigned short* XtB = Xt + (size_t)b * 68 * 68 * 64;
        const int ngr = NYA * 68 * 8;
        for (int g = tid; g < ngr; g += 256) {
            const int row = g / 544;
            const int rem = g - row * 544;
            const int rx = rem >> 3, gz = rem & 7;
            const int iyp = iy0 + row + 2;
            const s8 v = *(const s8*)(XtB + (((iyp * 68 + rx) * 8) + (gz ^ (rx & 7))) * 8);
            *(s8*)(Xs + ((row * 68 + rx) * 8 + gz) * 8) = v;
        }
    }
    __syncthreads();

    const int lane = tid & 63, lr = lane & 15, hi = lane >> 4;
    const int w = tid >> 6;
    const int p = w & 1, mq = w >> 1;
    const int obase = oh * 32 + mq * 16;

    if (p == 0)
        mfma_loop<PY, 0>(Xs, KA, KB, bias, out, b, oy, obase, lr, hi);
    else
        mfma_loop<PY, 1>(Xs, KA, KB, bias, out, b, oy, obase, lr, hi);
}

__global__ __launch_bounds__(256, 2) void fused_kernel(
    const unsigned short* __restrict__ Xt,
    const unsigned short* __restrict__ KA, const unsigned short* __restrict__ KB,
    const float* __restrict__ bias, float* __restrict__ out)
{
    __shared__ __align__(16) unsigned short Xs[4 * 68 * 64];
    const int z = blockIdx.z;
    const int oh = z >> 1;
    if (z & 1) fused_body<1>(Xt, KA, KB, bias, out, oh, Xs);
    else       fused_body<0>(Xt, KA, KB, bias, out, oh, Xs);
}

} // namespace

extern "C" void kernel_launch(void* const* d_in, const int* in_sizes, int n_in,
                              void* d_out, int out_size, void* d_ws, size_t ws_size,
                              hipStream_t stream)
{
    const float* x    = (const float*)d_in[0];
    const float* w0   = (const float*)d_in[1];
    const float* wc   = (const float*)d_in[2];
    const float* wsn  = (const float*)d_in[3];
    const float* wa   = (const float*)d_in[4];
    const float* bias = (const float*)d_in[5];
    float* out = (float*)d_out;

    char* wsb = (char*)d_ws;
    unsigned short* KA = (unsigned short*)(wsb);
    unsigned short* KB = (unsigned short*)(wsb + 802816);
    unsigned short* Xt = (unsigned short*)(wsb + 2097152);

    // host-side radial normalization constants (pure CPU math, capture-safe)
    float SA[3] = {0.f, 0.f, 0.f}, S5[3] = {0.f, 0.f, 0.f};
    for (int ky = 0; ky < 7; ++ky)
        for (int kx = 0; kx < 7; ++kx) {
            float dy = (float)(ky - 3), dx = (float)(kx - 3);
            float rr = sqrtf(dy * dy + dx * dx);
            for (int r = 0; r < 3; ++r) { float d = rr - (float)(r + 1); SA[r] += expf(-2.f * d * d); }
        }
    for (int ky = 0; ky < 5; ++ky)
        for (int kx = 0; kx < 5; ++kx) {
            float dy = (float)(ky - 2), dx = (float)(kx - 2);
            float rr = sqrtf(dy * dy + dx * dx);
            for (int r = 0; r < 3; ++r) { float d = rr - (float)r; S5[r] += expf(-2.f * d * d); }
        }

    prep_kernel<<<dim3(3568), dim3(256), 0, stream>>>(w0, wc, wsn, wa, KA, KB,
                                                      SA[0], SA[1], SA[2], S5[0], S5[1], S5[2]);
    transpose_kernel<<<dim3(68, 8), dim3(256), 0, stream>>>(x, Xt);
    fused_kernel<<<dim3(64, 8, 4), dim3(256), 0, stream>>>(Xt, KA, KB, bias, out);
}